// Round 16
// baseline (103.335 us; speedup 1.0000x reference)
//
#include <hip/hip_runtime.h>

// MoP fused kernel for MI355X (gfx950).
// B=65536, OBS=256, GOAL=64, S=16, H=128, A=32.
// d_out = [mixed (B*32 f32)] ++ [alphas (B*16 f32)]
// R16: skill loop on 32x32x16 MFMAs (72 vs 160 MFMA/skill/wave). W1/b1 rows
// stored bit2<->bit3-swapped so layer1's C feeds layer2's B-frag register-
// direct (k = 8*hi + j  <=>  acc reg 8q+j). Gate kept verbatim (16x16).

typedef __attribute__((ext_vector_type(8)))  short    bf16x8;  // 8 bf16, 4 VGPR
typedef __attribute__((ext_vector_type(4)))  float    f32x4;
typedef __attribute__((ext_vector_type(16))) float    f32x16;
typedef __attribute__((ext_vector_type(4)))  _Float16 f16x4;
typedef __attribute__((ext_vector_type(8)))  _Float16 f16x8;
using half2v = decltype(__builtin_amdgcn_cvt_pkrtz(0.f, 0.f));  // __fp16 x2

// ---- gate image (XOR-swizzled W, one-time use) ----
#define GATE_W1_OFF   0        // Wa1^T bf16: 128 rows x 640 B = 81920
#define GATE_W2_OFF   81920    // Wa2^T f16: 16 rows x 256 B = 4096
#define GATE_BA1_OFF  86016    // ba1 f32[128] = 512
#define GATE_BA2_OFF  86528    // ba2 f32[16]  = 64
#define GATE_BYTES    86592
// ---- skill images (pad-based, immediate-offset reads) ----
#define S_W1_STRIDE   528      // 128 rows -> 67584 B  (rows bit2<->3 swapped)
#define S_W2_OFF      67584    // 32 rows x 272 B = 8704 (natural k order)
#define S_W2_STRIDE   272
#define S_B1_OFF      76288    // b1 f32[128], slot-permuted (bit2<->3)
#define S_B2_OFF      76800    // b2 f32[32], slot-permuted for macc layout
#define S_IMG         76928
#define LDS_BYTES     163520   // bufA [0,86592) gate/odd skills, bufB [86592,+76928)

__device__ __forceinline__ unsigned short f2bf(float f) {
  unsigned u = __builtin_bit_cast(unsigned, f);
  return (unsigned short)((u + 0x7FFFu + ((u >> 16) & 1u)) >> 16);  // RNE
}

__device__ __forceinline__ bf16x8 pack_bf8(f32x4 a, f32x4 b) {
  int4 r;
  asm("v_cvt_pk_bf16_f32 %0, %1, %2" : "=v"(r.x) : "v"(a[0]), "v"(a[1]));
  asm("v_cvt_pk_bf16_f32 %0, %1, %2" : "=v"(r.y) : "v"(a[2]), "v"(a[3]));
  asm("v_cvt_pk_bf16_f32 %0, %1, %2" : "=v"(r.z) : "v"(b[0]), "v"(b[1]));
  asm("v_cvt_pk_bf16_f32 %0, %1, %2" : "=v"(r.w) : "v"(b[2]), "v"(b[3]));
  return __builtin_bit_cast(bf16x8, r);
}

// ---------------- weight prep: f32 -> bf16/f16 LDS images in ws -------------
__global__ void prep_weights(const float* __restrict__ Wa1, const float* __restrict__ Wa2,
                             const float* __restrict__ ba1, const float* __restrict__ ba2,
                             const float* __restrict__ W1,  const float* __restrict__ W2,
                             const float* __restrict__ b1,  const float* __restrict__ b2,
                             unsigned char* __restrict__ ws) {
  int i = blockIdx.x * 256 + threadIdx.x;
  if (i < 524288) {                       // W1 -> bf16 W1^T rows, bit2<->3 swap
    int s = i >> 15, r = i & 32767, h = r >> 8, o = r & 255;
    int hp = (h & ~12) | ((h & 4) << 1) | ((h & 8) >> 1);
    float v = W1[(s * 256 + o) * 128 + h];
    *(unsigned short*)(ws + GATE_BYTES + s * S_IMG + hp * S_W1_STRIDE + 2 * o) = f2bf(v);
  } else if (i < 589824) {                // W2 -> f16 W2^T rows (a), natural k
    int j = i - 524288, s = j >> 12, r = j & 4095, a = r >> 7, h = r & 127;
    float v = W2[(s * 128 + h) * 32 + a];
    *(_Float16*)(ws + GATE_BYTES + s * S_IMG + S_W2_OFF + a * S_W2_STRIDE + 2 * h) =
        (_Float16)v;
  } else if (i < 630784) {                // Wa1 -> bf16 Wa1^T rows, XOR swz (gate)
    int j = i - 589824, h = j / 320, o = j - h * 320;
    float v = Wa1[o * 128 + h];
    *(unsigned short*)(ws + GATE_W1_OFF + h * 640 +
                       ((2 * o) ^ ((h & 7) << 4))) = f2bf(v);
  } else if (i < 632832) {                // Wa2 -> f16 Wa2^T rows, XOR swz (gate)
    int j = i - 630784, n = j >> 7, h = j & 127;
    float v = Wa2[h * 16 + n];
    *(_Float16*)(ws + GATE_W2_OFF + n * 256 +
                 ((2 * h) ^ ((n & 7) << 3))) = (_Float16)v;
  } else if (i < 634880) {                // b1: store at bit2<->3-swapped slot
    int j = i - 632832, s = j >> 7, h = j & 127;
    int hp = (h & ~12) | ((h & 4) << 1) | ((h & 8) >> 1);
    *(float*)(ws + GATE_BYTES + s * S_IMG + S_B1_OFF + 4 * hp) = b1[s * 128 + h];
  } else if (i < 635392) {                // b2: slot p holds b2[s][a(p)]
    int j = i - 634880, s = j >> 5, p = j & 31;
    int a = (p & 3) | ((p & 4) << 1) | ((p & 8) << 1) | ((p & 16) >> 2);
    *(float*)(ws + GATE_BYTES + s * S_IMG + S_B2_OFF + 4 * p) = b2[s * 32 + a];
  } else if (i < 635520) {                // ba1 [128] f32 (gate)
    int j = i - 635392;
    *(float*)(ws + GATE_BA1_OFF + 4 * j) = ba1[j];
  } else if (i < 635536) {                // ba2 [16] f32 (gate)
    int j = i - 635520;
    *(float*)(ws + GATE_BA2_OFF + 4 * j) = ba2[j];
  }
}

__device__ __forceinline__ void stage_lin(const unsigned char* gsrc, unsigned char* ldst,
                                          int tid, int bytes) {
  for (int off = tid * 16; off < bytes; off += 512 * 16) {
    __builtin_amdgcn_global_load_lds(
        (const __attribute__((address_space(1))) unsigned int*)(const void*)(gsrc + off),
        (__attribute__((address_space(3))) unsigned int*)(void*)(ldst + off), 16, 0, 0);
  }
}

// ------------------------------- fused main ---------------------------------
// 256 blocks x 512 threads (8 waves, 2/SIMD), 1 block/CU, 256 batch rows/block,
// 32 rows per wave.
__global__ __launch_bounds__(512, 2)
void mop_fused(const float* __restrict__ obs, const float* __restrict__ goals,
               const unsigned char* __restrict__ ws, float* __restrict__ dout) {
  extern __shared__ unsigned char smem[];
  const int tid  = threadIdx.x;
  const int lane = tid & 63;
  const int wave = tid >> 6;          // 0..7
  const int l15  = lane & 15;
  const int g    = lane >> 4;
  const int r31  = lane & 31;
  const int hi   = lane >> 5;
  const int swz4 = (lane & 7) << 4;   // gate W1 swizzle
  const int swz3 = (lane & 7) << 3;   // gate W2 swizzle
  const int rowbase = blockIdx.x * 256 + wave * 32;

  float* out_mixed = dout;
  float* out_alpha = dout + 65536 * 32;

  // stage gate image into bufA
  stage_lin(ws, smem, tid, GATE_BYTES);

  const half2v zh = __builtin_amdgcn_cvt_pkrtz(0.f, 0.f);
  f32x4 alph[2];
  {
    // ---- gate phase: verbatim R12 (16x16 path), obs/goals scoped ----
    bf16x8 gobs[2][8];
    bf16x8 goalf[2][2];
    #pragma unroll
    for (int nb = 0; nb < 2; ++nb) {
      const float* rp = obs + (size_t)(rowbase + nb * 16 + l15) * 256 + 8 * g;
      #pragma unroll
      for (int t = 0; t < 8; ++t) {
        f32x4 a = *(const f32x4*)(rp + 32 * t);
        f32x4 c = *(const f32x4*)(rp + 32 * t + 4);
        gobs[nb][t] = pack_bf8(a, c);
      }
      const float* gp = goals + (size_t)(rowbase + nb * 16 + l15) * 64 + 8 * g;
      #pragma unroll
      for (int t = 0; t < 2; ++t) {
        f32x4 a = *(const f32x4*)(gp + 32 * t);
        f32x4 c = *(const f32x4*)(gp + 32 * t + 4);
        goalf[nb][t] = pack_bf8(a, c);
      }
    }

    __syncthreads();   // gate image resident
    // skill0 staging in flight during gate compute
    stage_lin(ws + GATE_BYTES, smem + GATE_BYTES, tid, S_IMG);

    f32x4 gacc[2][8];
    #pragma unroll
    for (int ht = 0; ht < 8; ++ht) {
      f32x4 bias = *(const f32x4*)(smem + GATE_BA1_OFF + 64 * ht + 16 * g);
      gacc[0][ht] = bias; gacc[1][ht] = bias;
    }
    #pragma unroll
    for (int t = 0; t < 10; ++t) {
      bf16x8 bf0 = (t < 8) ? gobs[0][t] : goalf[0][t - 8];
      bf16x8 bf1 = (t < 8) ? gobs[1][t] : goalf[1][t - 8];
      #pragma unroll
      for (int ht = 0; ht < 8; ++ht) {
        int row = 16 * ht + l15;
        bf16x8 af = *(const bf16x8*)(smem + GATE_W1_OFF + row * 640 +
                                     ((64 * t + 16 * g) ^ swz4));
        gacc[0][ht] = __builtin_amdgcn_mfma_f32_16x16x32_bf16(af, bf0, gacc[0][ht], 0, 0, 0);
        gacc[1][ht] = __builtin_amdgcn_mfma_f32_16x16x32_bf16(af, bf1, gacc[1][ht], 0, 0, 0);
      }
    }
    #pragma unroll
    for (int nb = 0; nb < 2; ++nb) {
      f32x4 lacc = *(const f32x4*)(smem + GATE_BA2_OFF + 16 * g);
      #pragma unroll
      for (int ht = 0; ht < 8; ++ht) {
        f32x4 v = gacc[nb][ht];
        f16x4 hf;
        {
          half2v lo_ = __builtin_amdgcn_cvt_pkrtz(v[0], v[1]);
          half2v hi_ = __builtin_amdgcn_cvt_pkrtz(v[2], v[3]);
          lo_ = __builtin_elementwise_max(lo_, zh);
          hi_ = __builtin_elementwise_max(hi_, zh);
          hf[0] = (_Float16)lo_[0]; hf[1] = (_Float16)lo_[1];
          hf[2] = (_Float16)hi_[0]; hf[3] = (_Float16)hi_[1];
        }
        f16x4 wf = *(const f16x4*)(smem + GATE_W2_OFF + l15 * 256 +
                                   ((32 * ht + 8 * g) ^ swz3));
        lacc = __builtin_amdgcn_mfma_f32_16x16x16f16(wf, hf, lacc, 0, 0, 0);
      }
      float m = fmaxf(fmaxf(lacc[0], lacc[1]), fmaxf(lacc[2], lacc[3]));
      m = fmaxf(m, __shfl_xor(m, 16, 64));
      m = fmaxf(m, __shfl_xor(m, 32, 64));
      f32x4 e;
      e[0] = __expf(lacc[0] - m); e[1] = __expf(lacc[1] - m);
      e[2] = __expf(lacc[2] - m); e[3] = __expf(lacc[3] - m);
      float ssum = e[0] + e[1] + e[2] + e[3];
      ssum += __shfl_xor(ssum, 16, 64);
      ssum += __shfl_xor(ssum, 32, 64);
      float inv = 1.0f / ssum;
      alph[nb] = e * inv;
      *(f32x4*)(out_alpha + (size_t)(rowbase + nb * 16 + l15) * 16 + 4 * g) = alph[nb];
    }
  }

  // obs fragments in 32-wide layout for the skill loop (L2/L3-warm re-read)
  // lane: batch row = r31; frag t: k = 16t + 8hi + j (j=0..7)
  bf16x8 obsf[16];
  {
    const float* rp2 = obs + (size_t)(rowbase + r31) * 256 + 8 * hi;
    #pragma unroll
    for (int t = 0; t < 16; ++t) {
      f32x4 a = *(const f32x4*)(rp2 + 16 * t);
      f32x4 c = *(const f32x4*)(rp2 + 16 * t + 4);
      obsf[t] = pack_bf8(a, c);
    }
  }

  __syncthreads();   // skill0 resident; all waves done with gate LDS region

  // per-lane skill-image bases
  const int lw1 = r31 * S_W1_STRIDE + 16 * hi;             // + ht*16896 + t*32
  const int lw2 = S_W2_OFF + r31 * S_W2_STRIDE + 16 * hi;  // + t*32

  // ---- skill loop: 32x32x16 MFMAs ----
  f32x16 macc = {};
  for (int s = 0; s < 16; ++s) {
    const unsigned char* buf = smem + ((s & 1) ? 0 : GATE_BYTES);
    if (s < 15) {
      unsigned char* nbuf = smem + (((s + 1) & 1) ? 0 : GATE_BYTES);
      stage_lin(ws + GATE_BYTES + (size_t)(s + 1) * S_IMG, nbuf, tid, S_IMG);
    }
    // alpha[s] for this lane's batch row (r31) via shfl from holding lane
    const int asrc = ((s >> 2) << 4) | l15;
    float p0 = (s & 1) ? alph[0][1] : alph[0][0];
    float p1 = (s & 1) ? alph[0][3] : alph[0][2];
    float as0 = __shfl((s & 2) ? p1 : p0, asrc, 64);
    float q0 = (s & 1) ? alph[1][1] : alph[1][0];
    float q1 = (s & 1) ? alph[1][3] : alph[1][2];
    float as1 = __shfl((s & 2) ? q1 : q0, asrc, 64);
    const float av = (r31 >> 4) ? as1 : as0;
    const half2v avh = __builtin_amdgcn_cvt_pkrtz(av, av);

    const unsigned char* w1p = buf + lw1;
    const unsigned char* w2p = buf + lw2;

    // acc init from slot-permuted b1 image
    f32x16 acc[4];
    #pragma unroll
    for (int ht = 0; ht < 4; ++ht) {
      f32x4 c0 = *(const f32x4*)(buf + S_B1_OFF + (32 * ht + 4 * hi) * 4);
      f32x4 c1 = *(const f32x4*)(buf + S_B1_OFF + (32 * ht + 8 + 4 * hi) * 4);
      f32x4 c2 = *(const f32x4*)(buf + S_B1_OFF + (32 * ht + 16 + 4 * hi) * 4);
      f32x4 c3 = *(const f32x4*)(buf + S_B1_OFF + (32 * ht + 24 + 4 * hi) * 4);
      acc[ht][0]  = c0[0]; acc[ht][1]  = c0[1]; acc[ht][2]  = c0[2]; acc[ht][3]  = c0[3];
      acc[ht][4]  = c1[0]; acc[ht][5]  = c1[1]; acc[ht][6]  = c1[2]; acc[ht][7]  = c1[3];
      acc[ht][8]  = c2[0]; acc[ht][9]  = c2[1]; acc[ht][10] = c2[2]; acc[ht][11] = c2[3];
      acc[ht][12] = c3[0]; acc[ht][13] = c3[1]; acc[ht][14] = c3[2]; acc[ht][15] = c3[3];
    }

    __builtin_amdgcn_s_setprio(1);
    // ---- layer 1: t-outer, 4 chains, 64 mfma_32x32x16_bf16 ----
    #pragma unroll
    for (int t = 0; t < 16; ++t) {
      const unsigned char* w1t = w1p + t * 32;
      #pragma unroll
      for (int ht = 0; ht < 4; ++ht) {
        bf16x8 af = *(const bf16x8*)(w1t + ht * 16896);   // imm offsets
        acc[ht] = __builtin_amdgcn_mfma_f32_32x32x16_bf16(af, obsf[t], acc[ht], 0, 0, 0);
      }
    }
    // ---- layer 2: 8 k-steps; C feeds B-frag register-direct (k=8hi+j <-> reg 8q+j)
    #pragma unroll
    for (int ht = 0; ht < 4; ++ht) {
      #pragma unroll
      for (int q = 0; q < 2; ++q) {
        const int t2 = 2 * ht + q;
        int4 w;
        {
          half2v h0 = __builtin_amdgcn_cvt_pkrtz(acc[ht][8 * q + 0], acc[ht][8 * q + 1]);
          half2v h1 = __builtin_amdgcn_cvt_pkrtz(acc[ht][8 * q + 2], acc[ht][8 * q + 3]);
          half2v h2 = __builtin_amdgcn_cvt_pkrtz(acc[ht][8 * q + 4], acc[ht][8 * q + 5]);
          half2v h3 = __builtin_amdgcn_cvt_pkrtz(acc[ht][8 * q + 6], acc[ht][8 * q + 7]);
          h0 = __builtin_elementwise_max(h0, zh) * avh;
          h1 = __builtin_elementwise_max(h1, zh) * avh;
          h2 = __builtin_elementwise_max(h2, zh) * avh;
          h3 = __builtin_elementwise_max(h3, zh) * avh;
          w.x = __builtin_bit_cast(int, h0); w.y = __builtin_bit_cast(int, h1);
          w.z = __builtin_bit_cast(int, h2); w.w = __builtin_bit_cast(int, h3);
        }
        f16x8 hf = __builtin_bit_cast(f16x8, w);
        f16x8 w2f = *(const f16x8*)(w2p + t2 * 32);
        macc = __builtin_amdgcn_mfma_f32_32x32x16_f16(w2f, hf, macc, 0, 0, 0);
      }
    }
    __builtin_amdgcn_s_setprio(0);
    // + alpha_s * b2[s] (slot-permuted image; zeros in this test)
    {
      f32x4 d0 = *(const f32x4*)(buf + S_B2_OFF + (16 * hi + 0) * 4);
      f32x4 d1 = *(const f32x4*)(buf + S_B2_OFF + (16 * hi + 4) * 4);
      f32x4 d2 = *(const f32x4*)(buf + S_B2_OFF + (16 * hi + 8) * 4);
      f32x4 d3 = *(const f32x4*)(buf + S_B2_OFF + (16 * hi + 12) * 4);
      macc[0]  += av * d0[0]; macc[1]  += av * d0[1]; macc[2]  += av * d0[2]; macc[3]  += av * d0[3];
      macc[4]  += av * d1[0]; macc[5]  += av * d1[1]; macc[6]  += av * d1[2]; macc[7]  += av * d1[3];
      macc[8]  += av * d2[0]; macc[9]  += av * d2[1]; macc[10] += av * d2[2]; macc[11] += av * d2[3];
      macc[12] += av * d3[0]; macc[13] += av * d3[1]; macc[14] += av * d3[2]; macc[15] += av * d3[3];
    }
    __syncthreads();   // drains next-skill stage (vmcnt) + releases buf
  }

  // ---- store mixed via padded-LDS bounce (C-layout -> row-major coalesced) ----
  // write: lane (batch r31) scatters 16 values to scratch[r31][a], stride 33
  unsigned char* scr = smem + wave * 4352;   // 32*33*4 = 4224 B per wave
  #pragma unroll
  for (int r = 0; r < 16; ++r) {
    const int a = (r & 3) | ((r & 4) << 1) | ((r & 8) << 1) | (hi << 2);
    *(float*)(scr + (r31 * 33 + a) * 4) = macc[r];
  }
  __syncthreads();
  const int r2 = lane >> 1, c16 = (lane & 1) * 16;
  #pragma unroll
  for (int k = 0; k < 4; ++k) {
    f32x4 v = *(const f32x4*)(scr + (r2 * 33 + c16 + 4 * k) * 4);
    *(f32x4*)(out_mixed + (size_t)(rowbase + r2) * 32 + c16 + 4 * k) = v;
  }
}

extern "C" void kernel_launch(void* const* d_in, const int* in_sizes, int n_in,
                              void* d_out, int out_size, void* d_ws, size_t ws_size,
                              hipStream_t stream) {
  const float* obs   = (const float*)d_in[0];
  const float* goals = (const float*)d_in[1];
  const float* Wa1   = (const float*)d_in[2];
  const float* ba1   = (const float*)d_in[3];
  const float* Wa2   = (const float*)d_in[4];
  const float* ba2   = (const float*)d_in[5];
  const float* W1    = (const float*)d_in[6];
  const float* b1    = (const float*)d_in[7];
  const float* W2    = (const float*)d_in[8];
  const float* b2    = (const float*)d_in[9];
  unsigned char* ws  = (unsigned char*)d_ws;
  float* out = (float*)d_out;

  prep_weights<<<2483, 256, 0, stream>>>(Wa1, Wa2, ba1, ba2, W1, W2, b1, b2, ws);
  mop_fused<<<256, 512, LDS_BYTES, stream>>>(obs, goals, ws, out);
}